// Round 8
// baseline (86.839 us; speedup 1.0000x reference)
//
#include <hip/hip_runtime.h>
#include <hip/hip_bf16.h>

typedef __bf16 bf16x8 __attribute__((ext_vector_type(8)));
typedef unsigned short u16x8 __attribute__((ext_vector_type(8)));
typedef unsigned int u32x4 __attribute__((ext_vector_type(4)));
typedef float f32x4 __attribute__((ext_vector_type(4)));

#define SLEN 2048
#define DDIM 128
#define NH   32
#define NKVH 8
#define QBLK 128   // 4 waves x 32 q-rows
#define KVB  32
#define KPAD 136
#define VPAD 40
#define PW2  20    // u32 row width of P-exchange slab
#define MINIT  -1e30f
#define MASKED -3e30f

static __device__ __forceinline__ unsigned short f2bfu(float f) {
  union { float f; unsigned u; } x; x.f = f;
  return (unsigned short)((x.u + 0x7fffu + ((x.u >> 16) & 1u)) >> 16);
}
static __device__ __forceinline__ float bfu2f(unsigned short u) {
  union { unsigned u; float f; } x; x.u = ((unsigned)u) << 16;
  return x.f;
}
static __device__ __forceinline__ unsigned cvt_pk_bf16(float lo, float hi) {
  unsigned r;
  asm("v_cvt_pk_bf16_f32 %0, %1, %2" : "=v"(r) : "v"(lo), "v"(hi));
  return r;  // lo -> D[15:0], hi -> D[31:16]
}
static __device__ __forceinline__ f32x4 mfma_bf16(u16x8 a, u16x8 b, f32x4 c) {
  return __builtin_amdgcn_mfma_f32_16x16x32_bf16(
      __builtin_bit_cast(bf16x8, a), __builtin_bit_cast(bf16x8, b), c, 0, 0, 0);
}

// ---- fused prepass: K -> bf16 (blocks 0..1023), V -> bf16 transposed (1024..3071) ----
__global__ __launch_bounds__(256) void conv_kv(const float* __restrict__ k,
                                               const float* __restrict__ v,
                                               unsigned* __restrict__ kdst,
                                               unsigned short* __restrict__ vt) {
  __shared__ unsigned T32[32][17];
  const int bb = blockIdx.x;
  if (bb < 1024) {   // K: 1024 x 256 x 8 = 2,097,152 = NKVH*SLEN*DDIM
    const int i = bb * 256 + threadIdx.x;
    const float4 f0 = ((const float4*)k)[2 * i];
    const float4 f1 = ((const float4*)k)[2 * i + 1];
    u32x4 o = { cvt_pk_bf16(f0.x, f0.y), cvt_pk_bf16(f0.z, f0.w),
                cvt_pk_bf16(f1.x, f1.y), cvt_pk_bf16(f1.z, f1.w) };
    ((u32x4*)kdst)[i] = o;
    return;
  }
  const int b   = bb - 1024;
  const int dt  = b & 3;
  const int st  = (b >> 2) & 63;
  const int kvh = b >> 8;
  const int r  = threadIdx.x >> 3;
  const int cg = threadIdx.x & 7;
  const float4 f = *(const float4*)(v + ((size_t)(kvh * SLEN + st * 32 + r) * DDIM) + dt * 32 + cg * 4);
  T32[r][cg * 2]     = cvt_pk_bf16(f.x, f.y);
  T32[r][cg * 2 + 1] = cvt_pk_bf16(f.z, f.w);
  __syncthreads();
  const int dr = threadIdx.x >> 3;
  const unsigned sel = (dr & 1) ? 0x07060302u : 0x05040100u;
  const unsigned a0 = T32[cg * 4 + 0][dr >> 1], a1 = T32[cg * 4 + 1][dr >> 1];
  const unsigned a2 = T32[cg * 4 + 2][dr >> 1], a3 = T32[cg * 4 + 3][dr >> 1];
  unsigned short* vp = vt + (size_t)kvh * DDIM * SLEN + (size_t)(dt * 32 + dr) * SLEN + st * 32 + cg * 4;
  const unsigned w0 = __builtin_amdgcn_perm(a1, a0, sel);
  const unsigned w1 = __builtin_amdgcn_perm(a3, a2, sel);
  vp[0] = (unsigned short)(w0 & 0xffff);
  vp[1] = (unsigned short)(w0 >> 16);
  vp[2] = (unsigned short)(w1 & 0xffff);
  vp[3] = (unsigned short)(w1 >> 16);
}

// ---- attention chunk kernel: 32 q-rows per wave (2 groups of 16) ----
__global__ __launch_bounds__(256, 3) void attn_fwd(
    const float* __restrict__ q, const unsigned short* __restrict__ kbf,
    const unsigned short* __restrict__ vtg, const float* __restrict__ sinks,
    const int* __restrict__ bwp, float* __restrict__ out,
    unsigned short* __restrict__ pO, float* __restrict__ pm,
    float* __restrict__ pl, const int nch) {
  __shared__ unsigned short Kl[KVB][KPAD];
  __shared__ unsigned short Vt[DDIM][VPAD];
  __shared__ unsigned Pex[4][2][16][PW2];   // [wave][group][q][k-pair slot]
  __shared__ float SmS[4][2][16];

  const int tid  = threadIdx.x;
  const int wid  = tid >> 6;
  const int lane = tid & 63;
  const int ln   = lane & 15;
  const int hi   = lane >> 4;

  const int B   = blockIdx.x;
  const int x   = B & 7;                 // XCD-resident kvh
  const int j   = B >> 3;
  const int per = 4 * nch;
  const int qt  = 15 - (j / per);        // descending: long chunks first
  const int rem = j % per;
  const int hh  = (nch == 2) ? (rem >> 1) : rem;
  const int c   = (nch == 2) ? (rem & 1) : 0;
  const int h   = x * 4 + hh;
  const int kvh = x;
  const int q0  = qt * QBLK;
  const int qrow0 = q0 + wid * 32;       // wave's 32 rows

  const int bwv    = bwp[0];
  const int lo_off = (bwv > 0) ? (bwv - 1) : SLEN;

  const int T0 = max(0, q0 - lo_off) >> 5;
  const int T1 = (q0 + QBLK - 1) >> 5;
  const int N  = T1 - T0 + 1;
  const int ch = (N + nch - 1) / nch;
  const int Ts = T0 + c * ch;
  const int Te = min(T1, Ts + ch - 1);

  const float sm_scale = 0.08838834764831845f;

  // ---- Q fragments: qf[g][dk], group g rows = qrow0 + g*16 + ln ----
  u16x8 qf[2][4];
  #pragma unroll
  for (int g = 0; g < 2; ++g) {
    const float* qp = q + ((size_t)(h * SLEN + qrow0 + g * 16 + ln) * DDIM) + hi * 8;
    #pragma unroll
    for (int dk = 0; dk < 4; ++dk) {
      float4 f0 = *(const float4*)(qp + dk * 32);
      float4 f1 = *(const float4*)(qp + dk * 32 + 4);
      u32x4 t = { cvt_pk_bf16(f0.x, f0.y), cvt_pk_bf16(f0.z, f0.w),
                  cvt_pk_bf16(f1.x, f1.y), cvt_pk_bf16(f1.z, f1.w) };
      qf[g][dk] = __builtin_bit_cast(u16x8, t);
    }
  }

  float m[2] = {MINIT, MINIT}, l[2] = {0.0f, 0.0f};
  f32x4 oacc[2][8];
  #pragma unroll
  for (int g = 0; g < 2; ++g)
    #pragma unroll
    for (int nt = 0; nt < 8; ++nt) oacc[g][nt] = f32x4{0.f, 0.f, 0.f, 0.f};

  const unsigned short* Kg = kbf + (size_t)kvh * SLEN * DDIM;
  const unsigned short* Vg = vtg + (size_t)kvh * DDIM * SLEN;

  const int kr0 = tid >> 4,          kc0 = (tid & 15) * 8;
  const int kr1 = (256 + tid) >> 4;
  const int vr0 = tid >> 2,          vc0 = (tid & 3) * 8;
  const int vr1 = (256 + tid) >> 2;

  const int kbS = Ts * 32, kbE = Te * 32;

  u16x8 pk0, pk1, pv0, pv1;
  {
    pk0 = *(const u16x8*)(Kg + (size_t)(kbS + kr0) * DDIM + kc0);
    pk1 = *(const u16x8*)(Kg + (size_t)(kbS + kr1) * DDIM + kc0);
    pv0 = *(const u16x8*)(Vg + (size_t)vr0 * SLEN + kbS + vc0);
    pv1 = *(const u16x8*)(Vg + (size_t)vr1 * SLEN + kbS + vc0);
  }

  for (int kb = kbS; kb <= kbE; kb += KVB) {
    __syncthreads();
    *(u16x8*)&Kl[kr0][kc0] = pk0;
    *(u16x8*)&Kl[kr1][kc0] = pk1;
    *(u16x8*)&Vt[vr0][vc0] = pv0;
    *(u16x8*)&Vt[vr1][vc0] = pv1;
    __syncthreads();

    {
      const int nb = min(kb + KVB, kbE);
      pk0 = *(const u16x8*)(Kg + (size_t)(nb + kr0) * DDIM + kc0);
      pk1 = *(const u16x8*)(Kg + (size_t)(nb + kr1) * DDIM + kc0);
      pv0 = *(const u16x8*)(Vg + (size_t)vr0 * SLEN + nb + vc0);
      pv1 = *(const u16x8*)(Vg + (size_t)vr1 * SLEN + nb + vc0);
    }

    if (kb > qrow0 + 31) continue;                  // above causal diag (wave)
    if (kb + KVB - 1 < qrow0 - lo_off) continue;    // before window (wave)

    // ---- QK^T swapped: each K-frag read feeds both q-groups ----
    f32x4 s00 = {0,0,0,0}, s01 = {0,0,0,0};  // krow 0..15: g0, g1
    f32x4 s10 = {0,0,0,0}, s11 = {0,0,0,0};  // krow 16..31
    #pragma unroll
    for (int dk = 0; dk < 4; ++dk) {
      const u16x8 kf = *(const u16x8*)&Kl[ln][dk*32 + hi*8];
      s00 = mfma_bf16(kf, qf[0][dk], s00);
      s01 = mfma_bf16(kf, qf[1][dk], s01);
    }
    #pragma unroll
    for (int dk = 0; dk < 4; ++dk) {
      const u16x8 kf = *(const u16x8*)&Kl[16 + ln][dk*32 + hi*8];
      s10 = mfma_bf16(kf, qf[0][dk], s10);
      s11 = mfma_bf16(kf, qf[1][dk], s11);
    }

    // ---- mask + scale, per group (lane's q-row = qrow0 + g*16 + ln) ----
    float p0[8], p1[8];
    const int qpos0 = qrow0 + ln, qpos1 = qrow0 + 16 + ln;
    #pragma unroll
    for (int r = 0; r < 4; ++r) {
      const int kp0 = kb + hi * 4 + r;
      const int kp1 = kp0 + 16;
      p0[r]     = ((kp0 <= qpos0) && (kp0 >= qpos0 - lo_off)) ? s00[r] * sm_scale : MASKED;
      p0[4 + r] = ((kp1 <= qpos0) && (kp1 >= qpos0 - lo_off)) ? s10[r] * sm_scale : MASKED;
      p1[r]     = ((kp0 <= qpos1) && (kp0 >= qpos1 - lo_off)) ? s01[r] * sm_scale : MASKED;
      p1[4 + r] = ((kp1 <= qpos1) && (kp1 >= qpos1 - lo_off)) ? s11[r] * sm_scale : MASKED;
    }

    // ---- row max per group: 7 in-reg + 2 shfl ----
    float mx0 = fmaxf(fmaxf(fmaxf(p0[0], p0[1]), fmaxf(p0[2], p0[3])),
                      fmaxf(fmaxf(p0[4], p0[5]), fmaxf(p0[6], p0[7])));
    float mx1 = fmaxf(fmaxf(fmaxf(p1[0], p1[1]), fmaxf(p1[2], p1[3])),
                      fmaxf(fmaxf(p1[4], p1[5]), fmaxf(p1[6], p1[7])));
    mx0 = fmaxf(mx0, __shfl_xor(mx0, 16));
    mx0 = fmaxf(mx0, __shfl_xor(mx0, 32));
    mx1 = fmaxf(mx1, __shfl_xor(mx1, 16));
    mx1 = fmaxf(mx1, __shfl_xor(mx1, 32));

    // ---- defer-max rescale (THR=8), combined trigger ----
    if (__any((mx0 > m[0] + 8.0f) || (mx1 > m[1] + 8.0f))) {
      const float mn0 = fmaxf(m[0], mx0), mn1 = fmaxf(m[1], mx1);
      const float c0 = __expf(m[0] - mn0), c1 = __expf(m[1] - mn1);
      l[0] *= c0; l[1] *= c1; m[0] = mn0; m[1] = mn1;
      if (hi == 0) { SmS[wid][0][ln] = c0; SmS[wid][1][ln] = c1; }
      float c40[4], c41[4];
      #pragma unroll
      for (int r = 0; r < 4; ++r) { c40[r] = SmS[wid][0][hi*4 + r]; c41[r] = SmS[wid][1][hi*4 + r]; }
      #pragma unroll
      for (int nt = 0; nt < 8; ++nt)
        #pragma unroll
        for (int r = 0; r < 4; ++r) { oacc[0][nt][r] *= c40[r]; oacc[1][nt][r] *= c41[r]; }
    }

    // ---- exp + row sum per group ----
    float s0 = 0.0f, s1 = 0.0f;
    #pragma unroll
    for (int jj = 0; jj < 8; ++jj) {
      p0[jj] = __expf(p0[jj] - m[0]); s0 += p0[jj];
      p1[jj] = __expf(p1[jj] - m[1]); s1 += p1[jj];
    }
    s0 += __shfl_xor(s0, 16); s0 += __shfl_xor(s0, 32); l[0] += s0;
    s1 += __shfl_xor(s1, 16); s1 += __shfl_xor(s1, 32); l[1] += s1;

    // ---- pack P per group into exchange slab ----
    Pex[wid][0][ln][hi * 2]         = cvt_pk_bf16(p0[0], p0[1]);
    Pex[wid][0][ln][hi * 2 + 1]     = cvt_pk_bf16(p0[2], p0[3]);
    Pex[wid][0][ln][8 + hi * 2]     = cvt_pk_bf16(p0[4], p0[5]);
    Pex[wid][0][ln][8 + hi * 2 + 1] = cvt_pk_bf16(p0[6], p0[7]);
    Pex[wid][1][ln][hi * 2]         = cvt_pk_bf16(p1[0], p1[1]);
    Pex[wid][1][ln][hi * 2 + 1]     = cvt_pk_bf16(p1[2], p1[3]);
    Pex[wid][1][ln][8 + hi * 2]     = cvt_pk_bf16(p1[4], p1[5]);
    Pex[wid][1][ln][8 + hi * 2 + 1] = cvt_pk_bf16(p1[6], p1[7]);
    const u16x8 pa0 = __builtin_bit_cast(u16x8, *(const u32x4*)&Pex[wid][0][ln][hi * 4]);
    const u16x8 pa1 = __builtin_bit_cast(u16x8, *(const u32x4*)&Pex[wid][1][ln][hi * 4]);

    // ---- PV: each V-frag read feeds both groups ----
    #pragma unroll
    for (int nt = 0; nt < 8; ++nt) {
      const u16x8 vb = *(const u16x8*)&Vt[nt*16 + ln][hi*8];
      oacc[0][nt] = mfma_bf16(pa0, vb, oacc[0][nt]);
      oacc[1][nt] = mfma_bf16(pa1, vb, oacc[1][nt]);
    }
  }

  // ---- epilogue ----
  if (nch == 1) {
    const float sink = sinks[h];
    #pragma unroll
    for (int g = 0; g < 2; ++g) {
      const float M  = fmaxf(m[g], sink);
      const float ed = __expf(m[g] - M);
      const float fac_ln = ed / (l[g] * ed + __expf(sink - M));
      if (hi == 0) SmS[wid][g][ln] = fac_ln;
      float fac4[4];
      #pragma unroll
      for (int r = 0; r < 4; ++r) fac4[r] = SmS[wid][g][hi * 4 + r];
      #pragma unroll
      for (int r = 0; r < 4; ++r) {
        float* op = out + ((size_t)(h * SLEN + qrow0 + g*16 + hi*4 + r) * DDIM) + ln;
        #pragma unroll
        for (int nt = 0; nt < 8; ++nt) op[nt * 16] = oacc[g][nt][r] * fac4[r];
      }
    }
  } else {
    const size_t Lb = ((size_t)(h * 16 + qt)) * 2 + c;
    #pragma unroll
    for (int g = 0; g < 2; ++g) {
      if (hi == 0) {
        pm[Lb * 128 + wid * 32 + g * 16 + ln] = m[g];
        pl[Lb * 128 + wid * 32 + g * 16 + ln] = l[g];
      }
      #pragma unroll
      for (int r = 0; r < 4; ++r) {
        unsigned short* po = pO + (Lb * 128 + wid * 32 + g * 16 + hi * 4 + r) * 128 + ln;
        #pragma unroll
        for (int nt = 0; nt < 8; ++nt) po[nt * 16] = f2bfu(oacc[g][nt][r]);
      }
    }
  }
}

// ---- merge two chunk partials + sink ----
__global__ __launch_bounds__(256) void merge2(
    const unsigned short* __restrict__ pO, const float* __restrict__ pm,
    const float* __restrict__ pl, const float* __restrict__ sinks,
    float* __restrict__ out) {
  const int blk  = blockIdx.x;             // 32 blocks per head x 64 rows
  const int h    = blk >> 5;
  const int rloc = (blk & 31) * 64 + (threadIdx.x >> 2);  // row within head
  const int d0   = (threadIdx.x & 3) * 32;
  const int qt   = rloc >> 7;
  const int lr   = rloc & 127;
  const size_t r0 = ((size_t)((h * 16 + qt) * 2 + 0)) * 128 + lr;
  const size_t r1 = r0 + 128;
  const float m0 = pm[r0], l0 = pl[r0];
  const float m1 = pm[r1], l1 = pl[r1];
  const float sink = sinks[h];
  const float M  = fmaxf(fmaxf(m0, m1), sink);
  const float e0 = __expf(m0 - M), e1 = __expf(m1 - M);
  const float inv = 1.0f / (l0 * e0 + l1 * e1 + __expf(sink - M));
  const float s0 = e0 * inv, s1 = e1 * inv;
  const unsigned short* p0 = pO + r0 * 128 + d0;
  const unsigned short* p1 = pO + r1 * 128 + d0;
  float* op = out + ((size_t)h * SLEN + rloc) * DDIM + d0;
  #pragma unroll
  for (int i = 0; i < 4; ++i) {
    u16x8 a = *(const u16x8*)(p0 + i * 8);
    u16x8 b = *(const u16x8*)(p1 + i * 8);
    float4 o0, o1;
    o0.x = bfu2f(a[0]) * s0 + bfu2f(b[0]) * s1;
    o0.y = bfu2f(a[1]) * s0 + bfu2f(b[1]) * s1;
    o0.z = bfu2f(a[2]) * s0 + bfu2f(b[2]) * s1;
    o0.w = bfu2f(a[3]) * s0 + bfu2f(b[3]) * s1;
    o1.x = bfu2f(a[4]) * s0 + bfu2f(b[4]) * s1;
    o1.y = bfu2f(a[5]) * s0 + bfu2f(b[5]) * s1;
    o1.z = bfu2f(a[6]) * s0 + bfu2f(b[6]) * s1;
    o1.w = bfu2f(a[7]) * s0 + bfu2f(b[7]) * s1;
    *(float4*)(op + i * 8)     = o0;
    *(float4*)(op + i * 8 + 4) = o1;
  }
}

extern "C" void kernel_launch(void* const* d_in, const int* in_sizes, int n_in,
                              void* d_out, int out_size, void* d_ws, size_t ws_size,
                              hipStream_t stream) {
  const float* q     = (const float*)d_in[0];
  const float* k     = (const float*)d_in[1];
  const float* v     = (const float*)d_in[2];
  const float* sinks = (const float*)d_in[3];
  const int*   bw    = (const int*)d_in[4];
  float* out = (float*)d_out;

  const size_t kvBytes = (size_t)NKVH * SLEN * DDIM * 2;
  unsigned short* kbf = (unsigned short*)d_ws;
  unsigned short* vtg = kbf + (size_t)NKVH * SLEN * DDIM;

  const size_t nPart   = (size_t)NH * 16 * 2 * 128;   // 131072 partial rows
  const size_t oBytes  = nPart * 128 * 2;
  const size_t mlBytes = nPart * 4 * 2;
  const size_t need2   = 2 * kvBytes + oBytes + mlBytes;

  const int nch = (ws_size >= need2) ? 2 : 1;

  unsigned short* pO = vtg + (size_t)NKVH * SLEN * DDIM;
  float* pm = (float*)((char*)pO + oBytes);
  float* pl = pm + nPart;

  conv_kv<<<dim3(1024 + NKVH * 64 * 4), 256, 0, stream>>>(k, v, (unsigned*)kbf, vtg);
  attn_fwd<<<dim3(512 * nch), 256, 0, stream>>>(q, kbf, vtg, sinks, bw, out,
                                                pO, pm, pl, nch);
  if (nch == 2)
    merge2<<<dim3(1024), 256, 0, stream>>>(pO, pm, pl, sinks, out);
}